// Round 1
// baseline (7771.224 us; speedup 1.0000x reference)
//
#include <hip/hip_runtime.h>
#include <math.h>

// Problem constants: T=64, B=128, H=256, C=256, K=8, L=3, rows = B*K = 1024.
// Workspace layout (floats):
static constexpr size_t O_EMBW   = 0;                    // [256][1024] emb@Wih0^T + bih0 + bhh0, unit-gate interleaved
static constexpr size_t O_WPT    = O_EMBW  + 262144;     // [256 k][256 c]
static constexpr size_t O_WIHT   = O_WPT   + 65536;      // [3][256 k][1024 (u*4+g)]
static constexpr size_t O_WHHT   = O_WIHT  + 786432;     // [3][256 k][1024]
static constexpr size_t O_BIASC  = O_WHHT  + 786432;     // [2][256 u][4 g]  (layers 1,2: bih+bhh)
static constexpr size_t O_STATE  = O_BIASC + 2048;       // [1024][256]
static constexpr size_t O_PREFIX = O_STATE + 262144;     // [1024]
static constexpr size_t O_H      = O_PREFIX+ 1024;       // [2 buf][3 l][1024][256]
static constexpr size_t O_C      = O_H     + 1572864;
static constexpr size_t O_PREV   = O_C     + 1572864;    // int [64][1024]
static constexpr size_t O_CLS    = O_PREV  + 65536;      // int [64][1024]
// total ≈ 5.44M floats ≈ 21.8 MB of d_ws

__device__ __forceinline__ float sigf(float x){ return 1.0f/(1.0f + expf(-x)); }

// ---------------- one-time prep: transposes + combined biases ----------------
__global__ __launch_bounds__(256) void k_prep(
    const float* __restrict__ Wih, const float* __restrict__ Whh,
    const float* __restrict__ Wp,  const float* __restrict__ bih,
    const float* __restrict__ bhh,
    float* __restrict__ wihT, float* __restrict__ whhT,
    float* __restrict__ WpT, float* __restrict__ biasC)
{
  const int NT = 786432;
  const int TOTAL = 2*NT + 65536 + 2048;
  int stride = gridDim.x * blockDim.x;
  for (int i = blockIdx.x*blockDim.x + threadIdx.x; i < TOTAL; i += stride){
    if (i < NT){
      int l = i / 262144, r = i % 262144;
      int k = r >> 10, cg = r & 1023, u = cg >> 2, g = cg & 3;
      wihT[i] = Wih[l*262144 + (g*256+u)*256 + k];
    } else if (i < 2*NT){
      int j = i - NT;
      int l = j / 262144, r = j % 262144;
      int k = r >> 10, cg = r & 1023, u = cg >> 2, g = cg & 3;
      whhT[j] = Whh[l*262144 + (g*256+u)*256 + k];
    } else if (i < 2*NT + 65536){
      int j = i - 2*NT; int k = j >> 8, c = j & 255;
      WpT[j] = Wp[c*256 + k];
    } else {
      int j = i - 2*NT - 65536;
      int l = 1 + (j >> 10); int cg = j & 1023, u = cg >> 2, g = cg & 3;
      biasC[j] = bih[l*1024 + g*256 + u] + bhh[l*1024 + g*256 + u];
    }
  }
}

// ---------------- one-time: embW[cls][u*4+g] = emb@Wih0^T + bih0 + bhh0 ------
__global__ __launch_bounds__(256) void k_embW(
    const float* __restrict__ emb, const float* __restrict__ wih0T,
    const float* __restrict__ bih, const float* __restrict__ bhh,
    float* __restrict__ embW)
{
  const int cls = blockIdx.x, u = threadIdx.x;
  const float* er = emb + cls*256;   // scalar (wave-uniform) reads
  float a0=0.f,a1=0.f,a2=0.f,a3=0.f;
  for (int k=0;k<256;k++){
    float ev = er[k];
    float4 w = *(const float4*)&wih0T[k*1024 + u*4];
    a0 = fmaf(ev, w.x, a0); a1 = fmaf(ev, w.y, a1);
    a2 = fmaf(ev, w.z, a2); a3 = fmaf(ev, w.w, a3);
  }
  a0 += bih[u]       + bhh[u];
  a1 += bih[256+u]   + bhh[256+u];
  a2 += bih[512+u]   + bhh[512+u];
  a3 += bih[768+u]   + bhh[768+u];
  *(float4*)&embW[cls*1024 + u*4] = make_float4(a0,a1,a2,a3);
}

// ---------------- init: state = x[0] broadcast, prefix init ------------------
__global__ __launch_bounds__(256) void k_init0(const float* __restrict__ x,
    float* __restrict__ state, float* __restrict__ prefix)
{
  int b = blockIdx.x, tid = threadIdx.x;
  float v = x[b*256 + tid];
  for (int k=0;k<8;k++) state[(size_t)(b*8+k)*256 + tid] = v;
  if (tid < 8) prefix[b*8+tid] = (tid==0) ? 0.0f : -1e30f;
}

// ---------------- init: one LSTM layer from zero state (h=0,c=0) -------------
__global__ __launch_bounds__(256) void k_initL(const float* __restrict__ in, int inMul,
    const float* __restrict__ wT, const float* __restrict__ bihl, const float* __restrict__ bhhl,
    float* __restrict__ Hout, float* __restrict__ Cout)
{
  int b = blockIdx.x, u = threadIdx.x;
  const float* ir = in + (size_t)b*inMul;
  float a0=0.f,a1=0.f,a2=0.f,a3=0.f;
  for (int k=0;k<256;k++){
    float xv = ir[k];
    float4 w = *(const float4*)&wT[k*1024 + u*4];
    a0=fmaf(xv,w.x,a0); a1=fmaf(xv,w.y,a1); a2=fmaf(xv,w.z,a2); a3=fmaf(xv,w.w,a3);
  }
  float gi = a0 + bihl[u]     + bhhl[u];
  float gg = a2 + bihl[512+u] + bhhl[512+u];
  float go = a3 + bihl[768+u] + bhhl[768+u];
  // c_old = 0 -> forget-gate term vanishes
  float cn = sigf(gi)*tanhf(gg);
  float hn = sigf(go)*tanhf(cn);
  for (int k=0;k<8;k++){
    Hout[(size_t)(b*8+k)*256+u]=hn;
    Cout[(size_t)(b*8+k)*256+u]=cn;
  }
}

// ------- per step: logits -> log_softmax -> joint -> top-8 (one wg/sample) ---
__global__ __launch_bounds__(256) void k_proj(
    const float* __restrict__ WpT, const float* __restrict__ bp,
    const float* __restrict__ state, float* __restrict__ prefix,
    int* __restrict__ prevH, int* __restrict__ clsH)
{
  const int b = blockIdx.x, tid = threadIdx.x, c = tid;
  const float* srow = state + (size_t)b*2048;   // 8 beams x 256, wave-uniform -> s_load
  float acc[8];
  #pragma unroll
  for (int i=0;i<8;i++) acc[i]=0.f;
  for (int k=0;k<256;k+=4){
    float w0 = WpT[(k+0)*256 + c];
    float w1 = WpT[(k+1)*256 + c];
    float w2 = WpT[(k+2)*256 + c];
    float w3 = WpT[(k+3)*256 + c];
    #pragma unroll
    for (int kb=0;kb<8;kb++){
      float4 sv = *(const float4*)&srow[kb*256 + k];
      acc[kb]=fmaf(sv.x,w0,acc[kb]); acc[kb]=fmaf(sv.y,w1,acc[kb]);
      acc[kb]=fmaf(sv.z,w2,acc[kb]); acc[kb]=fmaf(sv.w,w3,acc[kb]);
    }
  }
  __shared__ float jnt[2048];
  float bpc = bp[c];
  #pragma unroll
  for (int kb=0;kb<8;kb++) jnt[kb*256+c] = acc[kb]+bpc;
  __syncthreads();

  const int w = tid>>6, lane = tid&63;
  for (int rep=0;rep<2;rep++){
    int kb = w + rep*4;
    float4 v = *(const float4*)&jnt[kb*256 + lane*4];
    float m = fmaxf(fmaxf(v.x,v.y),fmaxf(v.z,v.w));
    for (int off=32;off;off>>=1) m = fmaxf(m, __shfl_down(m,off));
    m = __shfl(m, 0);
    double s = exp((double)v.x-(double)m)+exp((double)v.y-(double)m)
             + exp((double)v.z-(double)m)+exp((double)v.w-(double)m);
    for (int off=32;off;off>>=1) s += __shfl_down(s,off);
    s = __shfl(s, 0);
    double lse = log(s);
    float pf = prefix[b*8+kb];
    float4 o;
    o.x = (float)((double)v.x - (double)m - lse) + pf;
    o.y = (float)((double)v.y - (double)m - lse) + pf;
    o.z = (float)((double)v.z - (double)m - lse) + pf;
    o.w = (float)((double)v.w - (double)m - lse) + pf;
    *(float4*)&jnt[kb*256+lane*4] = o;
  }
  __syncthreads();

  __shared__ float bwv[4]; __shared__ int bwi[4];
  __shared__ int sPrev[8], sCls[8]; __shared__ float sVal[8];
  for (int r=0;r<8;r++){
    float bv = -INFINITY; int bi = 0;
    #pragma unroll
    for (int i=0;i<8;i++){
      int idx = tid*8+i; float v = jnt[idx];
      if (v > bv){ bv=v; bi=idx; }            // ascending scan: tie keeps lower idx
    }
    for (int off=32;off;off>>=1){
      float ov = __shfl_down(bv,off); int oi = __shfl_down(bi,off);
      if (ov>bv || (ov==bv && oi<bi)){ bv=ov; bi=oi; }
    }
    if (lane==0){ bwv[w]=bv; bwi[w]=bi; }
    __syncthreads();
    if (tid==0){
      float BV=bwv[0]; int BI=bwi[0];
      for (int j=1;j<4;j++) if (bwv[j]>BV || (bwv[j]==BV && bwi[j]<BI)){BV=bwv[j];BI=bwi[j];}
      sVal[r]=BV; sPrev[r]=BI>>8; sCls[r]=BI&255;
      jnt[BI] = -INFINITY;
    }
    __syncthreads();
  }
  if (tid<8){
    prefix[b*8+tid]=sVal[tid];
    prevH[b*8+tid]=sPrev[tid];
    clsH[b*8+tid]=sCls[tid];
  }
}

// --------- per step, per layer: gates GEMM + fused LSTM-cell epilogue --------
// out tile: 64 rows x 16 units (=64 gate-cols). 4 waves split K. 8x8 acc/thread.
__global__ __launch_bounds__(256) void k_lstm(
    const float* __restrict__ A1,    // dense input rows [1024][256] (h of layer l-1), null for l==0
    const float* __restrict__ Hold,  // h_old[l] [1024][256] (rows gathered via prev)
    const float* __restrict__ Cold,  // c_old[l]
    const float* __restrict__ WT1,   // wihT[l] [256][1024], null for l==0
    const float* __restrict__ WT2,   // whhT[l]
    const float* __restrict__ embW,  // l==0 C-init table, else null
    const float* __restrict__ biasC, // l>0 [256][4], else null
    const int* __restrict__ prev, const int* __restrict__ cls,
    float* __restrict__ Hnew, float* __restrict__ Cnew,
    float* __restrict__ state, const float* __restrict__ xT,   // l==2 only
    int KTOT)
{
  __shared__ float As[64*68];   // [k][row], stride 68, reused as reduce buf 0
  __shared__ float Bs[64*68];   // [k][u*4+g], reused as reduce buf 1
  const int tid = threadIdx.x;
  const int rb = (blockIdx.x & 15) << 6;
  const int ub = (blockIdx.x >> 4) << 4;
  // staging maps
  const int rq = tid & 15, kq = tid >> 4;
  const int r0s = rq*4, k0s = kq*4;            // A: 4 rows x 4 k, reg transpose
  const int kk2 = tid >> 2, cq = (tid & 3) << 4; // B: 1 k-row x 16 cols, direct
  // compute map
  const int w = tid >> 6, lane = tid & 63;
  const int r0 = (lane >> 3) * 8, c0 = (lane & 7) * 8;

  int grow[4];
  #pragma unroll
  for (int i=0;i<4;i++){
    int rg = rb + r0s + i;
    grow[i] = (rg & ~7) + prev[rg];
  }

  float acc[64];
  #pragma unroll
  for (int i=0;i<64;i++) acc[i]=0.f;

  const int nch = KTOT >> 6;
  float4 va0,va1,va2,va3, vb0,vb1,vb2,vb3;

  auto loadAB = [&](int kb){
    const bool haveA1 = (A1 != nullptr);
    const bool dense = haveA1 && (kb < 256);
    if (dense){
      const float* p = A1 + (size_t)(rb + r0s)*256 + kb + k0s;
      va0 = *(const float4*)(p);
      va1 = *(const float4*)(p + 256);
      va2 = *(const float4*)(p + 512);
      va3 = *(const float4*)(p + 768);
    } else {
      const int ko = kb - (haveA1 ? 256 : 0);
      va0 = *(const float4*)&Hold[(size_t)grow[0]*256 + ko + k0s];
      va1 = *(const float4*)&Hold[(size_t)grow[1]*256 + ko + k0s];
      va2 = *(const float4*)&Hold[(size_t)grow[2]*256 + ko + k0s];
      va3 = *(const float4*)&Hold[(size_t)grow[3]*256 + ko + k0s];
    }
    const float* WT; int kr;
    if (dense){ WT = WT1; kr = kb; }
    else { WT = WT2; kr = kb - (haveA1 ? 256 : 0); }
    const float* q = WT + (size_t)(kr + kk2)*1024 + ub*4 + cq;
    vb0 = *(const float4*)(q);
    vb1 = *(const float4*)(q+4);
    vb2 = *(const float4*)(q+8);
    vb3 = *(const float4*)(q+12);
  };
  auto storeAB = [&](){
    *(float4*)&As[(k0s+0)*68 + r0s] = make_float4(va0.x,va1.x,va2.x,va3.x);
    *(float4*)&As[(k0s+1)*68 + r0s] = make_float4(va0.y,va1.y,va2.y,va3.y);
    *(float4*)&As[(k0s+2)*68 + r0s] = make_float4(va0.z,va1.z,va2.z,va3.z);
    *(float4*)&As[(k0s+3)*68 + r0s] = make_float4(va0.w,va1.w,va2.w,va3.w);
    *(float4*)&Bs[kk2*68 + cq + 0]  = vb0;
    *(float4*)&Bs[kk2*68 + cq + 4]  = vb1;
    *(float4*)&Bs[kk2*68 + cq + 8]  = vb2;
    *(float4*)&Bs[kk2*68 + cq + 12] = vb3;
  };

  loadAB(0);
  for (int ch=0; ch<nch; ++ch){
    if (ch) __syncthreads();
    storeAB();
    __syncthreads();
    if (ch+1 < nch) loadAB((ch+1)<<6);
    const int kkb = w<<4;
    #pragma unroll
    for (int q2=0;q2<16;q2++){
      const int kk = kkb + q2;
      float a[8], bbv[8];
      *(float4*)&a[0]   = *(const float4*)&As[kk*68 + r0];
      *(float4*)&a[4]   = *(const float4*)&As[kk*68 + r0 + 4];
      *(float4*)&bbv[0] = *(const float4*)&Bs[kk*68 + c0];
      *(float4*)&bbv[4] = *(const float4*)&Bs[kk*68 + c0 + 4];
      #pragma unroll
      for (int i=0;i<8;i++)
        #pragma unroll
        for (int j=0;j<8;j++)
          acc[i*8+j] = fmaf(a[i], bbv[j], acc[i*8+j]);
    }
  }
  __syncthreads();

  // cross-wave split-K reduction into As (waves 0+1) and Bs (waves 2+3)
  #define ROFF(r,cl) ((r)*68 + ((((cl)>>3) ^ ((r)&7))<<3) + ((cl)&7))
  if (w==0 || w==2){
    float* red = (w==0) ? As : Bs;
    #pragma unroll
    for (int i=0;i<8;i++){
      *(float4*)&red[ROFF(r0+i, c0)]   = make_float4(acc[i*8+0],acc[i*8+1],acc[i*8+2],acc[i*8+3]);
      *(float4*)&red[ROFF(r0+i, c0+4)] = make_float4(acc[i*8+4],acc[i*8+5],acc[i*8+6],acc[i*8+7]);
    }
  }
  __syncthreads();
  if (w==1 || w==3){
    float* red = (w==1) ? As : Bs;
    #pragma unroll
    for (int i=0;i<8;i++){
      float4 p0 = *(float4*)&red[ROFF(r0+i, c0)];
      float4 p1 = *(float4*)&red[ROFF(r0+i, c0+4)];
      p0.x+=acc[i*8+0]; p0.y+=acc[i*8+1]; p0.z+=acc[i*8+2]; p0.w+=acc[i*8+3];
      p1.x+=acc[i*8+4]; p1.y+=acc[i*8+5]; p1.z+=acc[i*8+6]; p1.w+=acc[i*8+7];
      *(float4*)&red[ROFF(r0+i, c0)]   = p0;
      *(float4*)&red[ROFF(r0+i, c0+4)] = p1;
    }
  }
  __syncthreads();

  // epilogue: LSTM cell. thread: 1 row x 4 units
  {
    const int row = tid >> 2, tq = tid & 3;
    const int rowg = rb + row;
    const int gr = (rowg & ~7) + prev[rowg];
    const int u0 = tq*4;
    float4 co = *(const float4*)&Cold[(size_t)gr*256 + ub + u0];
    float cov[4] = {co.x,co.y,co.z,co.w};
    float hnv[4], cnv[4];
    const float* basep = (embW != nullptr)
        ? (embW + (size_t)cls[rowg]*1024 + (ub+u0)*4)
        : (biasC + (ub+u0)*4);
    #pragma unroll
    for (int q2=0;q2<4;q2++){
      int colL = (u0+q2)*4;
      float4 g0 = *(const float4*)&As[ROFF(row,colL)];
      float4 g1 = *(const float4*)&Bs[ROFF(row,colL)];
      float4 bs = *(const float4*)&basep[q2*4];
      float gi = g0.x+g1.x+bs.x;
      float gf = g0.y+g1.y+bs.y;
      float gg = g0.z+g1.z+bs.z;
      float go = g0.w+g1.w+bs.w;
      float cn = sigf(gf)*cov[q2] + sigf(gi)*tanhf(gg);
      float hn = sigf(go)*tanhf(cn);
      cnv[q2]=cn; hnv[q2]=hn;
    }
    size_t ob = (size_t)rowg*256 + ub + u0;
    *(float4*)&Hnew[ob] = make_float4(hnv[0],hnv[1],hnv[2],hnv[3]);
    *(float4*)&Cnew[ob] = make_float4(cnv[0],cnv[1],cnv[2],cnv[3]);
    if (state){
      const float4 xv = *(const float4*)&xT[(size_t)(rowg>>3)*256 + ub + u0];
      *(float4*)&state[ob] = make_float4(hnv[0]+xv.x, hnv[1]+xv.y, hnv[2]+xv.z, hnv[3]+xv.w);
    }
  }
  #undef ROFF
}

// ---------------- final: backtrace choices + copy prefix ---------------------
__global__ __launch_bounds__(256) void k_out(const int* __restrict__ prevH,
    const int* __restrict__ clsH, const float* __restrict__ prefix,
    float* __restrict__ out)
{
  int t0 = blockIdx.x*blockDim.x + threadIdx.x;  // (b*8+k)
  if (t0 >= 1024) return;
  int b = t0 >> 3, k = t0 & 7;
  int e = k;
  for (int t=63;t>=0;--t){
    int base = t*1024 + b*8;
    out[(size_t)t0*64 + t] = (float)clsH[base + e];
    e = prevH[base + e];
  }
  out[65536 + t0] = prefix[t0];
}

extern "C" void kernel_launch(void* const* d_in, const int* in_sizes, int n_in,
                              void* d_out, int out_size, void* d_ws, size_t ws_size,
                              hipStream_t stream)
{
  const float* x   = (const float*)d_in[0];  // [64][128][256]
  const float* emb = (const float*)d_in[1];  // [256][256]
  const float* Wih = (const float*)d_in[2];  // [3][1024][256]
  const float* Whh = (const float*)d_in[3];
  const float* bih = (const float*)d_in[4];  // [3][1024]
  const float* bhh = (const float*)d_in[5];
  const float* Wp  = (const float*)d_in[6];  // [256][256]
  const float* bp  = (const float*)d_in[7];  // [256]
  float* ws = (float*)d_ws;

  float* embW   = ws + O_EMBW;
  float* WpT    = ws + O_WPT;
  float* wihT   = ws + O_WIHT;
  float* whhT   = ws + O_WHHT;
  float* biasC  = ws + O_BIASC;
  float* state  = ws + O_STATE;
  float* prefix = ws + O_PREFIX;
  int*   prevH  = (int*)(ws + O_PREV);
  int*   clsH   = (int*)(ws + O_CLS);

  auto Hb = [&](int buf, int l){ return ws + O_H + (size_t)(buf*3+l)*262144; };
  auto Cb = [&](int buf, int l){ return ws + O_C + (size_t)(buf*3+l)*262144; };

  k_prep<<<256,256,0,stream>>>(Wih,Whh,Wp,bih,bhh,wihT,whhT,WpT,biasC);
  k_embW<<<256,256,0,stream>>>(emb, wihT, bih, bhh, embW);
  k_init0<<<128,256,0,stream>>>(x, state, prefix);
  k_initL<<<128,256,0,stream>>>(x,        256,  wihT,          bih,      bhh,      Hb(0,0), Cb(0,0));
  k_initL<<<128,256,0,stream>>>(Hb(0,0),  2048, wihT+262144,   bih+1024, bhh+1024, Hb(0,1), Cb(0,1));
  k_initL<<<128,256,0,stream>>>(Hb(0,1),  2048, wihT+524288,   bih+2048, bhh+2048, Hb(0,2), Cb(0,2));

  for (int t=0;t<64;t++){
    int cb = t&1, nb = cb^1;
    int* pv = prevH + t*1024;
    int* cl = clsH  + t*1024;
    k_proj<<<128,256,0,stream>>>(WpT, bp, state, prefix, pv, cl);
    // layer 0: K=256 (h-part only; x-part gathered from embW in epilogue)
    k_lstm<<<256,256,0,stream>>>(nullptr, Hb(cb,0), Cb(cb,0), nullptr, whhT, embW, nullptr,
                                 pv, cl, Hb(nb,0), Cb(nb,0), nullptr, nullptr, 256);
    // layer 1: K=512
    k_lstm<<<256,256,0,stream>>>(Hb(nb,0), Hb(cb,1), Cb(cb,1), wihT+262144, whhT+262144,
                                 nullptr, biasC, pv, cl, Hb(nb,1), Cb(nb,1), nullptr, nullptr, 512);
    // layer 2: K=512, + state = h + x[t_next]
    int tn = (t+1 < 64) ? (t+1) : 63;
    k_lstm<<<256,256,0,stream>>>(Hb(nb,1), Hb(cb,2), Cb(cb,2), wihT+524288, whhT+524288,
                                 nullptr, biasC+1024, pv, cl, Hb(nb,2), Cb(nb,2),
                                 state, x + (size_t)tn*32768, 512);
  }
  k_out<<<4,256,0,stream>>>(prevH, clsH, prefix, (float*)d_out);
}